// Round 13
// baseline (105.660 us; speedup 1.0000x reference)
//
#include <hip/hip_runtime.h>
#include <hip/hip_bf16.h>
#include <math.h>

#define B 64
#define L 64
#define NPT 127
#define D 128
#define VOCAB 30000
#define LABELS 30
#define SPLIT 4
#define KP 132    // padded LDS row stride (floats) for K/V tiles in k2 (16B-aligned)
#define WCS 136   // wcT row stride in ushorts (272B: 16B-aligned)

typedef __attribute__((ext_vector_type(8))) short bf16x8;
typedef __attribute__((ext_vector_type(4))) float f32x4;

__device__ __forceinline__ float bfhi(unsigned int u) {
  unsigned int x = u & 0xffff0000u;
  return __builtin_bit_cast(float, x);
}
__device__ __forceinline__ float bflo(unsigned int u) {
  unsigned int x = u << 16;
  return __builtin_bit_cast(float, x);
}
__device__ __forceinline__ unsigned short f2bf(float f) {
  __hip_bfloat16 h = __float2bfloat16(f);  // RNE
  return __builtin_bit_cast(unsigned short, h);
}

// ---------------------------------------------------------------------------
// K0 (MFMA): T[v][e] = bf16( sum_d emb[v][d]*Wc[d][e] + bc[e] )
// ---------------------------------------------------------------------------
__global__ __launch_bounds__(256) void k0_embWc(const float* __restrict__ emb,
                                                const float* __restrict__ Wc,
                                                const float* __restrict__ bc,
                                                __hip_bfloat16* __restrict__ T) {
  __shared__ unsigned short wcT[D * WCS];  // Wc^T bf16: wcT[e*WCS + d], ~34KB
  const int t = threadIdx.x;
  for (int i = t; i < D * D / 4; i += 256) {
    const int d = i >> 5;            // row of Wc
    const int e0 = (i & 31) * 4;     // 4 consecutive cols (lane-fast)
    float4 wv = *(const float4*)&Wc[d * D + e0];
    wcT[(e0 + 0) * WCS + d] = f2bf(wv.x);
    wcT[(e0 + 1) * WCS + d] = f2bf(wv.y);
    wcT[(e0 + 2) * WCS + d] = f2bf(wv.z);
    wcT[(e0 + 3) * WCS + d] = f2bf(wv.w);
  }
  __syncthreads();
  const int w = t >> 6, lane = t & 63;
  const int m = lane & 15;       // A-row / B-col within tile
  const int kg = lane >> 4;      // k-group 0..3
  int arow = blockIdx.x * 64 + w * 16 + m;
  if (arow >= VOCAB) arow = VOCAB - 1;  // clamp reads; stores guarded below
  const float* ap = emb + (size_t)arow * D + kg * 8;
  bf16x8 afrag[4];
#pragma unroll
  for (int kc = 0; kc < 4; ++kc) {
    float4 lo = *(const float4*)(ap + kc * 32);
    float4 hi = *(const float4*)(ap + kc * 32 + 4);
    union { bf16x8 v; unsigned short s[8]; } u;
    u.s[0] = f2bf(lo.x); u.s[1] = f2bf(lo.y); u.s[2] = f2bf(lo.z); u.s[3] = f2bf(lo.w);
    u.s[4] = f2bf(hi.x); u.s[5] = f2bf(hi.y); u.s[6] = f2bf(hi.z); u.s[7] = f2bf(hi.w);
    afrag[kc] = u.v;
  }
  const int grow0 = blockIdx.x * 64 + w * 16 + kg * 4;
#pragma unroll
  for (int ct = 0; ct < 8; ++ct) {
    const int col = ct * 16 + m;
    f32x4 acc = {0.f, 0.f, 0.f, 0.f};
#pragma unroll
    for (int kc = 0; kc < 4; ++kc) {
      bf16x8 bfrag = *(const bf16x8*)&wcT[col * WCS + kc * 32 + kg * 8];
      acc = __builtin_amdgcn_mfma_f32_16x16x32_bf16(afrag[kc], bfrag, acc, 0, 0, 0);
    }
    const float bcv = bc[col];
#pragma unroll
    for (int r = 0; r < 4; ++r) {
      const int grow = grow0 + r;
      if (grow < VOCAB)
        T[(size_t)grow * D + col] = __float2bfloat16(acc[r] + bcv);
    }
  }
}

// ---------------------------------------------------------------------------
// K1 (fused tree + qkv): 4 rows per 256-thread block (4 waves), 1024 blocks,
// launch_bounds(256,8) -> up to 32 waves/CU for gather latency hiding.
// Phase 1: one wave per row, scalar token loads, 8 static subtrees.
// Phase 2: thread -> (col t&127, group t>>7): g0 = Wq(4 rows)+Wv(rows 0,1),
// g1 = Wk(4 rows)+Wv(rows 2,3). Coalesced W loads, wave-uniform sEnc reads.
// ---------------------------------------------------------------------------
__global__ __launch_bounds__(256, 8) void k1_tree_qkv(
    const int* __restrict__ tokens, const __hip_bfloat16* __restrict__ T,
    const float* __restrict__ Wq, const float* __restrict__ Wk,
    const float* __restrict__ Wv, float* __restrict__ qb,
    float* __restrict__ kb, float* __restrict__ vb) {
  __shared__ float sEnc[4][D];
  const int t = threadIdx.x;
  const int w = __builtin_amdgcn_readfirstlane(t >> 6);  // wave id 0..3, SGPR
  const int lane = t & 63;
  const int row = blockIdx.x * 4 + w;                    // wave-uniform
  const int* __restrict__ tokrow = tokens + (size_t)row * NPT;
  const unsigned* Tp = (const unsigned*)T;  // one u32 = dim pair; row = 64 u32
  float m0 = -1e30f, m1 = -1e30f;
  float ra0[8], ra1[8];  // 8 subtree roots (level-3 nodes 7..14)
#pragma unroll
  for (int g = 0; g < 8; ++g) {
    unsigned nl[8], np[4], nq[2], nr;
#pragma unroll
    for (int i = 0; i < 8; ++i)
      nl[i] = Tp[(size_t)tokrow[63 + 8 * g + i] * 64 + lane];
#pragma unroll
    for (int i = 0; i < 4; ++i)
      np[i] = Tp[(size_t)tokrow[31 + 4 * g + i] * 64 + lane];
#pragma unroll
    for (int i = 0; i < 2; ++i)
      nq[i] = Tp[(size_t)tokrow[15 + 2 * g + i] * 64 + lane];
    nr = Tp[(size_t)tokrow[7 + g] * 64 + lane];
    float p0[4], p1[4];
#pragma unroll
    for (int i = 0; i < 4; ++i) {
      float a0 = bflo(nl[2 * i]), a1 = bfhi(nl[2 * i]);
      float b0 = bflo(nl[2 * i + 1]), b1 = bfhi(nl[2 * i + 1]);
      m0 = fmaxf(m0, fmaxf(a0, b0));
      m1 = fmaxf(m1, fmaxf(a1, b1));
      p0[i] = bflo(np[i]) + (a0 + b0);
      p1[i] = bfhi(np[i]) + (a1 + b1);
      m0 = fmaxf(m0, p0[i]);
      m1 = fmaxf(m1, p1[i]);
    }
    float q0[2], q1[2];
#pragma unroll
    for (int i = 0; i < 2; ++i) {
      q0[i] = bflo(nq[i]) + (p0[2 * i] + p0[2 * i + 1]);
      q1[i] = bfhi(nq[i]) + (p1[2 * i] + p1[2 * i + 1]);
      m0 = fmaxf(m0, q0[i]);
      m1 = fmaxf(m1, q1[i]);
    }
    ra0[g] = bflo(nr) + (q0[0] + q0[1]);
    ra1[g] = bfhi(nr) + (q1[0] + q1[1]);
    m0 = fmaxf(m0, ra0[g]);
    m1 = fmaxf(m1, ra1[g]);
  }
  unsigned ns[4], nt0, nt1, n0;
#pragma unroll
  for (int i = 0; i < 4; ++i) ns[i] = Tp[(size_t)tokrow[3 + i] * 64 + lane];
  nt0 = Tp[(size_t)tokrow[1] * 64 + lane];
  nt1 = Tp[(size_t)tokrow[2] * 64 + lane];
  n0 = Tp[(size_t)tokrow[0] * 64 + lane];
  float s0[4], s1[4];
#pragma unroll
  for (int i = 0; i < 4; ++i) {
    s0[i] = bflo(ns[i]) + (ra0[2 * i] + ra0[2 * i + 1]);
    s1[i] = bfhi(ns[i]) + (ra1[2 * i] + ra1[2 * i + 1]);
    m0 = fmaxf(m0, s0[i]);
    m1 = fmaxf(m1, s1[i]);
  }
  float ta0 = bflo(nt0) + (s0[0] + s0[1]);
  float ta1 = bfhi(nt0) + (s1[0] + s1[1]);
  float tb0 = bflo(nt1) + (s0[2] + s0[3]);
  float tb1 = bfhi(nt1) + (s1[2] + s1[3]);
  m0 = fmaxf(m0, fmaxf(ta0, tb0));
  m1 = fmaxf(m1, fmaxf(ta1, tb1));
  float v0 = bflo(n0) + (ta0 + tb0);
  float v1 = bfhi(n0) + (ta1 + tb1);
  m0 = fmaxf(m0, v0);
  m1 = fmaxf(m1, v1);
  sEnc[w][2 * lane] = fmaxf(m0, 0.0f);
  sEnc[w][2 * lane + 1] = fmaxf(m1, 0.0f);
  __syncthreads();
  // phase 2: col c for all threads; group 0 -> Wq(4)+Wv(0,1), group 1 -> Wk(4)+Wv(2,3)
  {
    const int c = t & 127;
    const int row0 = blockIdx.x * 4;
    if (t < 128) {
      float aq[4] = {}, av[2] = {};
#pragma unroll 8
      for (int k = 0; k < D; ++k) {
        float wq = Wq[k * D + c];    // coalesced
        float wv = Wv[k * D + c];
        float e0 = sEnc[0][k], e1 = sEnc[1][k], e2 = sEnc[2][k], e3 = sEnc[3][k];
        aq[0] += e0 * wq; aq[1] += e1 * wq; aq[2] += e2 * wq; aq[3] += e3 * wq;
        av[0] += e0 * wv; av[1] += e1 * wv;
      }
#pragma unroll
      for (int r = 0; r < 4; ++r) qb[(size_t)(row0 + r) * D + c] = aq[r];
      vb[(size_t)(row0 + 0) * D + c] = av[0];
      vb[(size_t)(row0 + 1) * D + c] = av[1];
    } else {
      float ak[4] = {}, av[2] = {};
#pragma unroll 8
      for (int k = 0; k < D; ++k) {
        float wk = Wk[k * D + c];    // coalesced
        float wv = Wv[k * D + c];
        float e0 = sEnc[0][k], e1 = sEnc[1][k], e2 = sEnc[2][k], e3 = sEnc[3][k];
        ak[0] += e0 * wk; ak[1] += e1 * wk; ak[2] += e2 * wk; ak[3] += e3 * wk;
        av[0] += e2 * wv; av[1] += e3 * wv;
      }
#pragma unroll
      for (int r = 0; r < 4; ++r) kb[(size_t)(row0 + r) * D + c] = ak[r];
      vb[(size_t)(row0 + 2) * D + c] = av[0];
      vb[(size_t)(row0 + 3) * D + c] = av[1];
    }
  }
}

// ---------------------------------------------------------------------------
// K2 (fused attn + Wo-proj + partial pool): one (batch, split of 16 q-rows)
// per block. Attention rows -> sOr LDS; proj with coalesced Wo loads;
// block writes 16-row pooled max to pool[b*SPLIT+sp].
// ---------------------------------------------------------------------------
__global__ __launch_bounds__(512) void k2_attn_proj(
    const float* __restrict__ qb, const float* __restrict__ kb,
    const float* __restrict__ vb, const int* __restrict__ mask,
    const float* __restrict__ Wo, float* __restrict__ pool) {
  __shared__ float sK[L * KP];      // 33.8 KB
  __shared__ float sV[L * KP];      // 33.8 KB
  __shared__ float sQ[8][D];        // 4 KB
  __shared__ float sOr[16][D];      // 8 KB
  __shared__ float pmax[4][D];      // 2 KB
  const int t = threadIdx.x;
  const int w = t >> 6, lane = t & 63;
  const int b = blockIdx.x / SPLIT;
  const int sp = blockIdx.x % SPLIT;
  for (int i = t * 4; i < L * D; i += 512 * 4) {
    int r = i >> 7, c = i & 127;
    float4 kv = *(const float4*)&kb[(size_t)(b * L + r) * D + c];
    float4 vv = *(const float4*)&vb[(size_t)(b * L + r) * D + c];
    *(float4*)&sK[r * KP + c] = kv;
    *(float4*)&sV[r * KP + c] = vv;
  }
  __syncthreads();
#pragma unroll
  for (int it = 0; it < 2; ++it) {
    const int r = sp * 16 + w * 2 + it;
    float2 qv = *(const float2*)&qb[(size_t)(b * L + r) * D + lane * 2];
    sQ[w][lane * 2] = qv.x;
    sQ[w][lane * 2 + 1] = qv.y;
    float sc = 0.f;
    const float4* kr = (const float4*)&sK[lane * KP];
    const float4* qr = (const float4*)&sQ[w][0];
#pragma unroll 8
    for (int k4 = 0; k4 < 32; ++k4) {
      float4 kv = kr[k4];
      float4 q4 = qr[k4];
      sc += q4.x * kv.x + q4.y * kv.y + q4.z * kv.z + q4.w * kv.w;
    }
    sc *= 0.08838834764831845f;
    if (mask[((size_t)b * L + r) * L + lane] <= 0) sc = -1e9f;
    float mx = sc;
#pragma unroll
    for (int off = 32; off >= 1; off >>= 1) mx = fmaxf(mx, __shfl_xor(mx, off));
    float ex = __expf(sc - mx);
    float sm = ex;
#pragma unroll
    for (int off = 32; off >= 1; off >>= 1) sm += __shfl_xor(sm, off);
    float a = ex / sm;
    float o0 = 0.f, o1 = 0.f;
#pragma unroll
    for (int j = 0; j < L; ++j) {
      float aj = __shfl(a, j);
      o0 += aj * sV[j * KP + lane];
      o1 += aj * sV[j * KP + lane + 64];
    }
    sOr[w * 2 + it][lane] = o0;
    sOr[w * 2 + it][lane + 64] = o1;
  }
  __syncthreads();
  // Wo projection: thread -> (col c, row group rg of 4 rows); coalesced Wo.
  {
    const int c = t & 127;
    const int rg = t >> 7;  // 0..3
    float acc[4] = {};
#pragma unroll 4
    for (int k = 0; k < D; ++k) {
      float wv = Wo[k * D + c];   // coalesced across 128 lanes
#pragma unroll
      for (int r = 0; r < 4; ++r) acc[r] += sOr[rg * 4 + r][k] * wv;
    }
    float pm = fmaxf(fmaxf(acc[0], acc[1]), fmaxf(acc[2], acc[3]));
    pmax[rg][c] = pm;
  }
  __syncthreads();
  if (t < 128) {
    float pv = fmaxf(fmaxf(pmax[0][t], pmax[1][t]), fmaxf(pmax[2][t], pmax[3][t]));
    pool[(size_t)blockIdx.x * D + t] = pv;
  }
}

// ---------------------------------------------------------------------------
// K3: final pooled max over splits + logits
// ---------------------------------------------------------------------------
__global__ __launch_bounds__(128) void k3_logits(const float* __restrict__ pool,
                                                 const float* __restrict__ Wl,
                                                 const float* __restrict__ bl,
                                                 float* __restrict__ out) {
  __shared__ float sP[D];
  const int b = blockIdx.x, t = threadIdx.x;
  float pv = pool[((size_t)b * SPLIT) * D + t];
#pragma unroll
  for (int i = 1; i < SPLIT; ++i)
    pv = fmaxf(pv, pool[((size_t)b * SPLIT + i) * D + t]);
  sP[t] = pv;
  __syncthreads();
  if (t < LABELS) {
    float a = bl[t];
#pragma unroll 4
    for (int d = 0; d < D; ++d) a += sP[d] * Wl[d * LABELS + t];
    out[b * LABELS + t] = a;
  }
}

extern "C" void kernel_launch(void* const* d_in, const int* in_sizes, int n_in,
                              void* d_out, int out_size, void* d_ws, size_t ws_size,
                              hipStream_t stream) {
  const int* tokens = (const int*)d_in[0];
  const int* mask = (const int*)d_in[1];
  const float* emb = (const float*)d_in[2];
  const float* Wc = (const float*)d_in[3];
  const float* bc = (const float*)d_in[4];
  const float* Wq = (const float*)d_in[5];
  const float* Wk = (const float*)d_in[6];
  const float* Wv = (const float*)d_in[7];
  const float* Wo = (const float*)d_in[8];
  const float* Wl = (const float*)d_in[9];
  const float* bl = (const float*)d_in[10];
  float* out = (float*)d_out;

  __hip_bfloat16* T = (__hip_bfloat16*)d_ws;        // VOCAB*D bf16 = 7.68 MB
  float* qb = (float*)(T + (size_t)VOCAB * D);      // B*L*D f32 each
  float* kb = qb + (size_t)B * L * D;
  float* vb = kb + (size_t)B * L * D;
  float* pool = vb + (size_t)B * L * D;             // B*SPLIT*D

  hipLaunchKernelGGL(k0_embWc, dim3((VOCAB + 63) / 64), dim3(256), 0, stream,
                     emb, Wc, bc, T);
  hipLaunchKernelGGL(k1_tree_qkv, dim3(B * L / 4), dim3(256), 0, stream,
                     tokens, T, Wq, Wk, Wv, qb, kb, vb);
  hipLaunchKernelGGL(k2_attn_proj, dim3(B * SPLIT), dim3(512), 0, stream,
                     qb, kb, vb, mask, Wo, pool);
  hipLaunchKernelGGL(k3_logits, dim3(B), dim3(128), 0, stream,
                     pool, Wl, bl, out);
}

// Round 14
// 75.080 us; speedup vs baseline: 1.4073x; 1.4073x over previous
//
#include <hip/hip_runtime.h>
#include <hip/hip_bf16.h>
#include <math.h>

#define B 64
#define L 64
#define NPT 127
#define D 128
#define VOCAB 30000
#define LABELS 30
#define SPLIT 4
#define KP 132    // padded LDS row stride (floats) for K/V tiles in k2 (16B-aligned)
#define WCS 136   // wcT row stride in ushorts (272B: 16B-aligned)

typedef __attribute__((ext_vector_type(8))) short bf16x8;
typedef __attribute__((ext_vector_type(4))) float f32x4;

__device__ __forceinline__ float bfhi(unsigned int u) {
  unsigned int x = u & 0xffff0000u;
  return __builtin_bit_cast(float, x);
}
__device__ __forceinline__ float bflo(unsigned int u) {
  unsigned int x = u << 16;
  return __builtin_bit_cast(float, x);
}
__device__ __forceinline__ unsigned short f2bf(float f) {
  __hip_bfloat16 h = __float2bfloat16(f);  // RNE
  return __builtin_bit_cast(unsigned short, h);
}

// ---------------------------------------------------------------------------
// K0 (MFMA): T[v][e] = bf16( sum_d emb[v][d]*Wc[d][e] + bc[e] )
// ---------------------------------------------------------------------------
__global__ __launch_bounds__(256) void k0_embWc(const float* __restrict__ emb,
                                                const float* __restrict__ Wc,
                                                const float* __restrict__ bc,
                                                __hip_bfloat16* __restrict__ T) {
  __shared__ unsigned short wcT[D * WCS];  // Wc^T bf16: wcT[e*WCS + d], ~34KB
  const int t = threadIdx.x;
  for (int i = t; i < D * D / 4; i += 256) {
    const int d = i >> 5;            // row of Wc
    const int e0 = (i & 31) * 4;     // 4 consecutive cols (lane-fast)
    float4 wv = *(const float4*)&Wc[d * D + e0];
    wcT[(e0 + 0) * WCS + d] = f2bf(wv.x);
    wcT[(e0 + 1) * WCS + d] = f2bf(wv.y);
    wcT[(e0 + 2) * WCS + d] = f2bf(wv.z);
    wcT[(e0 + 3) * WCS + d] = f2bf(wv.w);
  }
  __syncthreads();
  const int w = t >> 6, lane = t & 63;
  const int m = lane & 15;       // A-row / B-col within tile
  const int kg = lane >> 4;      // k-group 0..3
  int arow = blockIdx.x * 64 + w * 16 + m;
  if (arow >= VOCAB) arow = VOCAB - 1;  // clamp reads; stores guarded below
  const float* ap = emb + (size_t)arow * D + kg * 8;
  bf16x8 afrag[4];
#pragma unroll
  for (int kc = 0; kc < 4; ++kc) {
    float4 lo = *(const float4*)(ap + kc * 32);
    float4 hi = *(const float4*)(ap + kc * 32 + 4);
    union { bf16x8 v; unsigned short s[8]; } u;
    u.s[0] = f2bf(lo.x); u.s[1] = f2bf(lo.y); u.s[2] = f2bf(lo.z); u.s[3] = f2bf(lo.w);
    u.s[4] = f2bf(hi.x); u.s[5] = f2bf(hi.y); u.s[6] = f2bf(hi.z); u.s[7] = f2bf(hi.w);
    afrag[kc] = u.v;
  }
  const int grow0 = blockIdx.x * 64 + w * 16 + kg * 4;
#pragma unroll
  for (int ct = 0; ct < 8; ++ct) {
    const int col = ct * 16 + m;
    f32x4 acc = {0.f, 0.f, 0.f, 0.f};
#pragma unroll
    for (int kc = 0; kc < 4; ++kc) {
      bf16x8 bfrag = *(const bf16x8*)&wcT[col * WCS + kc * 32 + kg * 8];
      acc = __builtin_amdgcn_mfma_f32_16x16x32_bf16(afrag[kc], bfrag, acc, 0, 0, 0);
    }
    const float bcv = bc[col];
#pragma unroll
    for (int r = 0; r < 4; ++r) {
      const int grow = grow0 + r;
      if (grow < VOCAB)
        T[(size_t)grow * D + col] = __float2bfloat16(acc[r] + bcv);
    }
  }
}

// ---------------------------------------------------------------------------
// K1 (fused tree + qkv): 512 blocks x 1024 threads (16 waves). 8 rows per
// block, TWO waves per row: half h computes subtrees g=4h..4h+3 (60 gather
// loads, 15-deep static ILP), writes 4 subtree roots + partial max to LDS;
// wave A does the 7-node top combine. 2 blocks/CU = 32 waves/CU (2x R10).
// FP order bit-identical to R10. Phase 2 = R10's coalesced qkv (t<384).
// ---------------------------------------------------------------------------
__global__ __launch_bounds__(1024, 8) void k1_tree_qkv(
    const int* __restrict__ tokens, const __hip_bfloat16* __restrict__ T,
    const float* __restrict__ Wq, const float* __restrict__ Wk,
    const float* __restrict__ Wv, float* __restrict__ qb,
    float* __restrict__ kb, float* __restrict__ vb) {
  __shared__ float sR0[8][8][64];   // [row][g][lane] subtree root, dim 2*lane
  __shared__ float sR1[8][8][64];   // dim 2*lane+1
  __shared__ float sPM0[8][2][64];  // partial max per half
  __shared__ float sPM1[8][2][64];
  __shared__ float sEnc[8][D];
  const int t = threadIdx.x;
  const int wv_ = __builtin_amdgcn_readfirstlane(t >> 6);  // wave 0..15
  const int lane = t & 63;
  const int rw = wv_ >> 1;          // row within block 0..7
  const int half = wv_ & 1;         // subtree half
  const int row = blockIdx.x * 8 + rw;
  const int* __restrict__ tokrow = tokens + (size_t)row * NPT;
  const unsigned* Tp = (const unsigned*)T;  // one u32 = dim pair; row = 64 u32
  float m0 = -1e30f, m1 = -1e30f;
#pragma unroll
  for (int gi = 0; gi < 4; ++gi) {
    const int g = half * 4 + gi;
    unsigned nl[8], np[4], nq[2], nr;
#pragma unroll
    for (int i = 0; i < 8; ++i)
      nl[i] = Tp[(size_t)tokrow[63 + 8 * g + i] * 64 + lane];
#pragma unroll
    for (int i = 0; i < 4; ++i)
      np[i] = Tp[(size_t)tokrow[31 + 4 * g + i] * 64 + lane];
#pragma unroll
    for (int i = 0; i < 2; ++i)
      nq[i] = Tp[(size_t)tokrow[15 + 2 * g + i] * 64 + lane];
    nr = Tp[(size_t)tokrow[7 + g] * 64 + lane];
    float p0[4], p1[4];
#pragma unroll
    for (int i = 0; i < 4; ++i) {
      float a0 = bflo(nl[2 * i]), a1 = bfhi(nl[2 * i]);
      float b0 = bflo(nl[2 * i + 1]), b1 = bfhi(nl[2 * i + 1]);
      m0 = fmaxf(m0, fmaxf(a0, b0));
      m1 = fmaxf(m1, fmaxf(a1, b1));
      p0[i] = bflo(np[i]) + (a0 + b0);
      p1[i] = bfhi(np[i]) + (a1 + b1);
      m0 = fmaxf(m0, p0[i]);
      m1 = fmaxf(m1, p1[i]);
    }
    float q0[2], q1[2];
#pragma unroll
    for (int i = 0; i < 2; ++i) {
      q0[i] = bflo(nq[i]) + (p0[2 * i] + p0[2 * i + 1]);
      q1[i] = bfhi(nq[i]) + (p1[2 * i] + p1[2 * i + 1]);
      m0 = fmaxf(m0, q0[i]);
      m1 = fmaxf(m1, q1[i]);
    }
    float r0 = bflo(nr) + (q0[0] + q0[1]);
    float r1 = bfhi(nr) + (q1[0] + q1[1]);
    m0 = fmaxf(m0, r0);
    m1 = fmaxf(m1, r1);
    sR0[rw][g][lane] = r0;
    sR1[rw][g][lane] = r1;
  }
  sPM0[rw][half][lane] = m0;
  sPM1[rw][half][lane] = m1;
  __syncthreads();
  if (half == 0) {
    // top combine: nodes 3..6, 1..2, 0 (7 scalar-token loads)
    unsigned ns[4], nt0, nt1, n0;
#pragma unroll
    for (int i = 0; i < 4; ++i) ns[i] = Tp[(size_t)tokrow[3 + i] * 64 + lane];
    nt0 = Tp[(size_t)tokrow[1] * 64 + lane];
    nt1 = Tp[(size_t)tokrow[2] * 64 + lane];
    n0 = Tp[(size_t)tokrow[0] * 64 + lane];
    float M0 = fmaxf(sPM0[rw][0][lane], sPM0[rw][1][lane]);
    float M1 = fmaxf(sPM1[rw][0][lane], sPM1[rw][1][lane]);
    float s0[4], s1[4];
#pragma unroll
    for (int i = 0; i < 4; ++i) {
      s0[i] = bflo(ns[i]) + (sR0[rw][2 * i][lane] + sR0[rw][2 * i + 1][lane]);
      s1[i] = bfhi(ns[i]) + (sR1[rw][2 * i][lane] + sR1[rw][2 * i + 1][lane]);
      M0 = fmaxf(M0, s0[i]);
      M1 = fmaxf(M1, s1[i]);
    }
    float ta0 = bflo(nt0) + (s0[0] + s0[1]);
    float ta1 = bfhi(nt0) + (s1[0] + s1[1]);
    float tb0 = bflo(nt1) + (s0[2] + s0[3]);
    float tb1 = bfhi(nt1) + (s1[2] + s1[3]);
    M0 = fmaxf(M0, fmaxf(ta0, tb0));
    M1 = fmaxf(M1, fmaxf(ta1, tb1));
    float v0 = bflo(n0) + (ta0 + tb0);
    float v1 = bfhi(n0) + (ta1 + tb1);
    M0 = fmaxf(M0, v0);
    M1 = fmaxf(M1, v1);
    sEnc[rw][2 * lane] = fmaxf(M0, 0.0f);
    sEnc[rw][2 * lane + 1] = fmaxf(M1, 0.0f);
  }
  __syncthreads();
  if (t < 384) {
    const int mi = t >> 7;        // 0=q, 1=k, 2=v
    const int c = t & 127;
    const float* W = mi == 0 ? Wq : (mi == 1 ? Wk : Wv);
    float* outb = mi == 0 ? qb : (mi == 1 ? kb : vb);
    float acc[8] = {};
#pragma unroll 8
    for (int k = 0; k < D; ++k) {
      float wvv = W[k * D + c];   // coalesced across 128 lanes
#pragma unroll
      for (int r = 0; r < 8; ++r) acc[r] += sEnc[r][k] * wvv;  // broadcasts
    }
    const int row0 = blockIdx.x * 8;
#pragma unroll
    for (int r = 0; r < 8; ++r)
      outb[(size_t)(row0 + r) * D + c] = acc[r];
  }
}

// ---------------------------------------------------------------------------
// K2 (fused attn + Wo-proj + partial pool): one (batch, split of 16 q-rows)
// per block. Attention rows -> sOr LDS; proj with coalesced Wo loads;
// block writes 16-row pooled max to pool[b*SPLIT+sp].
// ---------------------------------------------------------------------------
__global__ __launch_bounds__(512) void k2_attn_proj(
    const float* __restrict__ qb, const float* __restrict__ kb,
    const float* __restrict__ vb, const int* __restrict__ mask,
    const float* __restrict__ Wo, float* __restrict__ pool) {
  __shared__ float sK[L * KP];      // 33.8 KB
  __shared__ float sV[L * KP];      // 33.8 KB
  __shared__ float sQ[8][D];        // 4 KB
  __shared__ float sOr[16][D];      // 8 KB
  __shared__ float pmax[4][D];      // 2 KB
  const int t = threadIdx.x;
  const int w = t >> 6, lane = t & 63;
  const int b = blockIdx.x / SPLIT;
  const int sp = blockIdx.x % SPLIT;
  for (int i = t * 4; i < L * D; i += 512 * 4) {
    int r = i >> 7, c = i & 127;
    float4 kv = *(const float4*)&kb[(size_t)(b * L + r) * D + c];
    float4 vv = *(const float4*)&vb[(size_t)(b * L + r) * D + c];
    *(float4*)&sK[r * KP + c] = kv;
    *(float4*)&sV[r * KP + c] = vv;
  }
  __syncthreads();
#pragma unroll
  for (int it = 0; it < 2; ++it) {
    const int r = sp * 16 + w * 2 + it;
    float2 qv = *(const float2*)&qb[(size_t)(b * L + r) * D + lane * 2];
    sQ[w][lane * 2] = qv.x;
    sQ[w][lane * 2 + 1] = qv.y;
    float sc = 0.f;
    const float4* kr = (const float4*)&sK[lane * KP];
    const float4* qr = (const float4*)&sQ[w][0];
#pragma unroll 8
    for (int k4 = 0; k4 < 32; ++k4) {
      float4 kv = kr[k4];
      float4 q4 = qr[k4];
      sc += q4.x * kv.x + q4.y * kv.y + q4.z * kv.z + q4.w * kv.w;
    }
    sc *= 0.08838834764831845f;
    if (mask[((size_t)b * L + r) * L + lane] <= 0) sc = -1e9f;
    float mx = sc;
#pragma unroll
    for (int off = 32; off >= 1; off >>= 1) mx = fmaxf(mx, __shfl_xor(mx, off));
    float ex = __expf(sc - mx);
    float sm = ex;
#pragma unroll
    for (int off = 32; off >= 1; off >>= 1) sm += __shfl_xor(sm, off);
    float a = ex / sm;
    float o0 = 0.f, o1 = 0.f;
#pragma unroll
    for (int j = 0; j < L; ++j) {
      float aj = __shfl(a, j);
      o0 += aj * sV[j * KP + lane];
      o1 += aj * sV[j * KP + lane + 64];
    }
    sOr[w * 2 + it][lane] = o0;
    sOr[w * 2 + it][lane + 64] = o1;
  }
  __syncthreads();
  // Wo projection: thread -> (col c, row group rg of 4 rows); coalesced Wo.
  {
    const int c = t & 127;
    const int rg = t >> 7;  // 0..3
    float acc[4] = {};
#pragma unroll 4
    for (int k = 0; k < D; ++k) {
      float wv = Wo[k * D + c];   // coalesced across 128 lanes
#pragma unroll
      for (int r = 0; r < 4; ++r) acc[r] += sOr[rg * 4 + r][k] * wv;
    }
    float pm = fmaxf(fmaxf(acc[0], acc[1]), fmaxf(acc[2], acc[3]));
    pmax[rg][c] = pm;
  }
  __syncthreads();
  if (t < 128) {
    float pv = fmaxf(fmaxf(pmax[0][t], pmax[1][t]), fmaxf(pmax[2][t], pmax[3][t]));
    pool[(size_t)blockIdx.x * D + t] = pv;
  }
}

// ---------------------------------------------------------------------------
// K3: final pooled max over splits + logits
// ---------------------------------------------------------------------------
__global__ __launch_bounds__(128) void k3_logits(const float* __restrict__ pool,
                                                 const float* __restrict__ Wl,
                                                 const float* __restrict__ bl,
                                                 float* __restrict__ out) {
  __shared__ float sP[D];
  const int b = blockIdx.x, t = threadIdx.x;
  float pv = pool[((size_t)b * SPLIT) * D + t];
#pragma unroll
  for (int i = 1; i < SPLIT; ++i)
    pv = fmaxf(pv, pool[((size_t)b * SPLIT + i) * D + t]);
  sP[t] = pv;
  __syncthreads();
  if (t < LABELS) {
    float a = bl[t];
#pragma unroll 4
    for (int d = 0; d < D; ++d) a += sP[d] * Wl[d * LABELS + t];
    out[b * LABELS + t] = a;
  }
}

extern "C" void kernel_launch(void* const* d_in, const int* in_sizes, int n_in,
                              void* d_out, int out_size, void* d_ws, size_t ws_size,
                              hipStream_t stream) {
  const int* tokens = (const int*)d_in[0];
  const int* mask = (const int*)d_in[1];
  const float* emb = (const float*)d_in[2];
  const float* Wc = (const float*)d_in[3];
  const float* bc = (const float*)d_in[4];
  const float* Wq = (const float*)d_in[5];
  const float* Wk = (const float*)d_in[6];
  const float* Wv = (const float*)d_in[7];
  const float* Wo = (const float*)d_in[8];
  const float* Wl = (const float*)d_in[9];
  const float* bl = (const float*)d_in[10];
  float* out = (float*)d_out;

  __hip_bfloat16* T = (__hip_bfloat16*)d_ws;        // VOCAB*D bf16 = 7.68 MB
  float* qb = (float*)(T + (size_t)VOCAB * D);      // B*L*D f32 each
  float* kb = qb + (size_t)B * L * D;
  float* vb = kb + (size_t)B * L * D;
  float* pool = vb + (size_t)B * L * D;             // B*SPLIT*D

  hipLaunchKernelGGL(k0_embWc, dim3((VOCAB + 63) / 64), dim3(256), 0, stream,
                     emb, Wc, bc, T);
  hipLaunchKernelGGL(k1_tree_qkv, dim3(B * L / 8), dim3(1024), 0, stream,
                     tokens, T, Wq, Wk, Wv, qb, kb, vb);
  hipLaunchKernelGGL(k2_attn_proj, dim3(B * SPLIT), dim3(512), 0, stream,
                     qb, kb, vb, mask, Wo, pool);
  hipLaunchKernelGGL(k3_logits, dim3(B), dim3(128), 0, stream,
                     pool, Wl, bl, out);
}